// Round 1
// baseline (565.579 us; speedup 1.0000x reference)
//
#include <hip/hip_runtime.h>
#include <math.h>

// ---------------------------------------------------------------------------
// TannerGNN. Round 16: k_msg occupancy + barrier surgery. LDS 76.3KB -> 50.5KB
// (3 blocks/CU instead of 2): sW double-buffered (16KB) and staged via async
// global_load_lds (wreg[12] register file deleted); phases A+B unified into a
// single 12-chunk pipeline with ONE barrier per chunk (24 -> 12 staging
// barriers); phase C + segmented reduction split into two 64-feature passes so
// sMsg is 128x68 f32 (34.8KB). MFMA order / bias / relu math unchanged.
// Reduction strips are now 16 edges (was 32) -> runs crossing new boundaries
// issue one extra f32 atomic (1e-7-level associativity shift in agg only).
// k_prep/sort/k_gru/k_readout identical to R15.
// N_NODES=50000, N_EDGES=400000, H=128, L=3, T=2, FEAT=4, N_DATA=40000.
// ---------------------------------------------------------------------------

#define H 128
#define TE2 128        // edges per message block
#define MS3 68         // sMsg row stride in f32 (64 cols used per half-pass)
#define HS  136        // sHid/sIn row stride in bf16
#define EXS 132        // sEx row stride in f32 (2-way banks)
#define FEAT 4
#define WG_PER_LAYER 196608   // 2 mat * 2 split * 4 kc * 24 jtg * 64 lane * 8
#define WR_TOTAL 32768        // 2 split * 4 kc * 8 jtg * 64 lane * 8
#define WC_TOTAL 294912       // 6 lt * 12 chunk * 4096

typedef __bf16 bf16x8 __attribute__((ext_vector_type(8)));
typedef __bf16 bf16x4 __attribute__((ext_vector_type(4)));
typedef float  f32x4  __attribute__((ext_vector_type(4)));

// async global->LDS, 16B per lane; l must be the wave-uniform base
// (HW writes lane i at l + i*16), g is the per-lane global address.
__device__ __forceinline__ void gload_lds16(const void* g, void* l) {
    __builtin_amdgcn_global_load_lds(
        (const __attribute__((address_space(1))) void*)g,
        (__attribute__((address_space(3))) void*)l, 16, 0, 0);
}

// ---------------- mega-prep: weight swizzles + cnt zero + input proj -------
__global__ __launch_bounds__(256) void k_prep(
    const float* __restrict__ W1, const float* __restrict__ W2,
    const float* __restrict__ Wih, const float* __restrict__ Whh,
    const float* __restrict__ Wr1,
    const float* __restrict__ x, const float* __restrict__ Win,
    const float* __restrict__ bin,
    __bf16* __restrict__ Wsw, __bf16* __restrict__ Wg,
    __bf16* __restrict__ Wr1s, int* __restrict__ cnt,
    float* __restrict__ h, __bf16* __restrict__ hb,
    float* __restrict__ agg, int n_nodes)
{
    const int N1 = WC_TOTAL;
    const int N2 = 3 * WG_PER_LAYER;
    const int N3 = WR_TOTAL;
    const int N4 = 2 * n_nodes;
    const long long N5 = (long long)n_nodes * H;
    long long gid = (long long)blockIdx.x * 256 + threadIdx.x;

    if (gid < N1) {
        int g = (int)gid;
        const int per_lt = 12 * 4096;
        int lt = g / per_lt, rem = g % per_lt;
        int chunk = rem >> 12;
        int within = rem & 4095;
        int ct = within >> 9;
        int lane = (within >> 3) & 63;
        int j = within & 7;
        int r = lane & 15, quad = lane >> 4;
        int n = ct * 16 + r;
        float v;
        if (chunk < 8) {
            int k = chunk * 32 + quad * 8 + j;
            v = W1[((size_t)lt * 256 + k) * 128 + n];
        } else {
            int k = (chunk - 8) * 32 + quad * 8 + j;
            v = W2[((size_t)lt * 128 + k) * 128 + n];
        }
        Wsw[g] = (__bf16)v;
        return;
    }
    gid -= N1;
    if (gid < N2) {
        int g = (int)gid;
        int layer = g / WG_PER_LAYER, rem = g % WG_PER_LAYER;
        int t = rem & 7;
        int lane = (rem >> 3) & 63;
        int jtg = (rem >> 9) % 24;
        int mk = rem / 12288;          // (mat*2+split)*4 + kc
        int kc = mk & 3;
        int msplit = mk >> 2;
        int mat = msplit >> 1, split = msplit & 1;
        int r = lane & 15, quad = lane >> 4;
        int k = kc * 32 + quad * 8 + t;
        int n = jtg * 16 + r;
        const float* W = (mat ? Whh : Wih) + (size_t)layer * 128 * 384;
        float v = W[(size_t)k * 384 + n];
        __bf16 hi = (__bf16)v;
        Wg[g] = split ? (__bf16)(v - (float)hi) : hi;
        return;
    }
    gid -= N2;
    if (gid < N3) {
        int g = (int)gid;
        int t = g & 7;
        int lane = (g >> 3) & 63;
        int jtg = (g >> 9) & 7;
        int kc = (g >> 12) & 3;
        int split = g >> 14;
        int r = lane & 15, quad = lane >> 4;
        int k = kc * 32 + quad * 8 + t;
        int n = jtg * 16 + r;
        float v = Wr1[(size_t)k * H + n];
        __bf16 hi = (__bf16)v;
        Wr1s[g] = split ? (__bf16)(v - (float)hi) : hi;
        return;
    }
    gid -= N3;
    if (gid < N4) {
        cnt[(int)gid] = 0;
        return;
    }
    gid -= N4;
    if (gid < N5) {
        int idx = (int)gid;
        int n = idx >> 7, j = idx & 127;
        float acc = bin[j];
#pragma unroll
        for (int f = 0; f < FEAT; f++)
            acc += x[n * FEAT + f] * Win[f * H + j];
        float v = fmaxf(acc, 0.f);
        h[idx] = v;
        hb[idx] = (__bf16)v;
        agg[idx] = 0.f;
    }
}

// ---------------- counting sort by key = type*nn + dst ---------------------
__global__ __launch_bounds__(256) void k_hist(
    const int* __restrict__ et, const int* __restrict__ dst,
    int* __restrict__ cnt, int n_edges, int nn)
{
    int i = blockIdx.x * 256 + threadIdx.x;
    if (i < n_edges) atomicAdd(&cnt[et[i] * nn + dst[i]], 1);
}

__global__ __launch_bounds__(1024) void k_scan1(
    const int* __restrict__ cnt, int* __restrict__ bsum, int n)
{
    int i = blockIdx.x * 1024 + threadIdx.x;
    int v = (i < n) ? cnt[i] : 0;
#pragma unroll
    for (int off = 32; off > 0; off >>= 1) v += __shfl_down(v, off, 64);
    __shared__ int ws[16];
    int lane = threadIdx.x & 63, w = threadIdx.x >> 6;
    if (lane == 0) ws[w] = v;
    __syncthreads();
    if (threadIdx.x < 16) {
        int x = ws[threadIdx.x];
#pragma unroll
        for (int off = 8; off > 0; off >>= 1) x += __shfl_down(x, off, 64);
        if (threadIdx.x == 0) bsum[blockIdx.x] = x;
    }
}

__global__ __launch_bounds__(128) void k_scan2(
    int* __restrict__ bsum, int* __restrict__ offs, int nb, int n)
{
    int lane = threadIdx.x & 63, w = threadIdx.x >> 6;
    int v = (threadIdx.x < nb) ? bsum[threadIdx.x] : 0;
    int orig = v;
#pragma unroll
    for (int off = 1; off < 64; off <<= 1) {
        int t = __shfl_up(v, off, 64);
        if (lane >= off) v += t;
    }
    __shared__ int w0sum;
    if (threadIdx.x == 63) w0sum = v;
    __syncthreads();
    int ex = v - orig + (w ? w0sum : 0);
    if (threadIdx.x < nb) bsum[threadIdx.x] = ex;
    if (threadIdx.x == nb - 1) offs[n] = ex + orig;
}

__global__ __launch_bounds__(1024) void k_scan3(
    const int* __restrict__ cnt, const int* __restrict__ bsum,
    int* __restrict__ offs, int n)
{
    int i = blockIdx.x * 1024 + threadIdx.x;
    int v = (i < n) ? cnt[i] : 0;
    int orig = v;
    int lane = threadIdx.x & 63, w = threadIdx.x >> 6;
#pragma unroll
    for (int off = 1; off < 64; off <<= 1) {
        int t = __shfl_up(v, off, 64);
        if (lane >= off) v += t;
    }
    __shared__ int ws[16];
    if (lane == 63) ws[w] = v;
    __syncthreads();
    if (threadIdx.x < 16) {
        int x = ws[threadIdx.x];
#pragma unroll
        for (int off = 1; off < 16; off <<= 1) {
            int t = __shfl_up(x, off, 64);
            if (lane >= off) x += t;
        }
        ws[threadIdx.x] = x;
    }
    __syncthreads();
    int wbase = w ? ws[w - 1] : 0;
    if (i < n) offs[i] = bsum[blockIdx.x] + wbase + v - orig;
}

__global__ __launch_bounds__(256) void k_place(
    const int* __restrict__ et, const int* __restrict__ dst,
    const int* __restrict__ offs, int* __restrict__ cnt,
    int* __restrict__ bucket, int n_edges, int nn)
{
    int i = blockIdx.x * 256 + threadIdx.x;
    if (i < n_edges) {
        int key = et[i] * nn + dst[i];
        int p = atomicAdd(&cnt[key], -1) - 1;
        bucket[offs[key] + p] = i;
    }
}

// ---------------- fused MFMA message kernel --------------------------------
// R16: 12-chunk unified pipeline, double-buffered async weight staging,
// half-width phase-C/reduction passes. LDS = 16384 + 34816 + 512 = 51712 B
// -> 3 blocks/CU. One barrier per chunk; 15 barriers/block total (was 26).
__global__ __launch_bounds__(512, 6) void k_msg(
    const __bf16* __restrict__ hb,
    const int* __restrict__ bucket, const int* __restrict__ offs,
    const int* __restrict__ src, const int* __restrict__ dst,
    const __bf16* __restrict__ Wsw, const float* __restrict__ b1l,
    const float* __restrict__ b2l,
    float* __restrict__ agg, int n_edges, int nn)
{
    const int t = blockIdx.y;
    const int c0 = offs[nn];
    const int cnt = t ? (n_edges - c0) : c0;
    const int base = t ? c0 : 0;
    const int start = blockIdx.x * TE2;
    if (start >= cnt) return;

    const __bf16* __restrict__ W = Wsw + (size_t)t * 12 * 4096;
    const float*  __restrict__ b1 = b1l + t * H;
    const float*  __restrict__ b2 = b2l + t * H;

    __shared__ __bf16 sW[2][4096];         // 16 KB double-buffered weight chunk
    __shared__ float  sMsg[TE2 * MS3];     // 34816 B; sHid strips alias per-wave
    __shared__ int    sDstV[TE2];

    const int tid  = threadIdx.x;
    const int lane = tid & 63;
    const int w    = tid >> 6;
    const int r    = lane & 15;
    const int quad = lane >> 4;

    // async-stage chunk 0 into sW[0]: wave-uniform LDS base + lane*16
    gload_lds16(W + (size_t)tid * 8,
                (char*)(&sW[0][0]) + (size_t)w * 1024);

    if (tid < TE2) {
        int i = start + tid;
        sDstV[tid] = (i < cnt) ? dst[bucket[base + i]] : -1;
    }

    int ei = start + w * 16 + r;
    int e = bucket[base + (ei < cnt ? ei : cnt - 1)];
    const __bf16* aps = hb + (size_t)src[e] * H;
    const __bf16* apd = hb + (size_t)dst[e] * H;

    bf16x8 afS[4];
#pragma unroll
    for (int i = 0; i < 4; i++)
        afS[i] = *(const bf16x8*)(aps + i * 32 + quad * 8);

    // per-wave private strip: 16 rows x HS(136) bf16 = 4352 B = 16*MS3*4 B
    __bf16* sHid = (__bf16*)((char*)sMsg + (size_t)w * (16 * HS * 2));

    f32x4 acc[8];
#pragma unroll
    for (int ct = 0; ct < 8; ct++) acc[ct] = (f32x4){0.f, 0.f, 0.f, 0.f};
    f32x4 acc2[8];
    bf16x8 afD[4];

    // ---- unified 12-chunk pipeline: A (kc 0..7, K=256) then B (kc 8..11) --
#pragma unroll
    for (int kc = 0; kc < 12; kc++) {
        __syncthreads();   // sW[kc&1] landed (vmcnt drain); prior reads done
        if (kc < 11)
            gload_lds16(W + (size_t)(kc + 1) * 4096 + (size_t)tid * 8,
                        (char*)(&sW[(kc + 1) & 1][0]) + (size_t)w * 1024);
        const __bf16* cw = &sW[kc & 1][0];
        if (kc < 8) {
            if (kc == 2) {
#pragma unroll
                for (int i = 0; i < 4; i++)
                    afD[i] = *(const bf16x8*)(apd + i * 32 + quad * 8);
            }
            bf16x8 b = (kc < 4) ? afS[kc] : afD[kc - 4];
#pragma unroll
            for (int ct = 0; ct < 8; ct++) {
                bf16x8 a = *(const bf16x8*)(cw + ct * 512 + lane * 8);
                acc[ct] = __builtin_amdgcn_mfma_f32_16x16x32_bf16(a, b, acc[ct], 0, 0, 0);
            }
            if (kc == 7) {
                // epilogue A: bias + relu -> bf16 -> own-wave sHid strip
#pragma unroll
                for (int ct = 0; ct < 8; ct++) {
                    f32x4 bb4 = *(const f32x4*)(b1 + ct * 16 + quad * 4);
                    bf16x4 hv;
#pragma unroll
                    for (int g = 0; g < 4; g++)
                        hv[g] = (__bf16)fmaxf(acc[ct][g] + bb4[g], 0.f);
                    *(bf16x4*)(sHid + r * HS + ct * 16 + quad * 4) = hv;
                }
#pragma unroll
                for (int ct = 0; ct < 8; ct++) acc2[ct] = (f32x4){0.f, 0.f, 0.f, 0.f};
            }
        } else {
            bf16x8 b = *(const bf16x8*)(sHid + r * HS + (kc - 8) * 32 + quad * 8);
#pragma unroll
            for (int ct = 0; ct < 8; ct++) {
                bf16x8 a = *(const bf16x8*)(cw + ct * 512 + lane * 8);
                acc2[ct] = __builtin_amdgcn_mfma_f32_16x16x32_bf16(a, b, acc2[ct], 0, 0, 0);
            }
        }
    }

    // ---- phase C + segmented reduction: two 64-feature passes -------------
    // half=0 writes features 0..63 into the wave's OWN strip rows (same bytes
    // its sHid occupied; only this wave ever read them -> same-wave DS order
    // suffices, no barrier). half=1 must wait for pass-0 reduction reads.
#pragma unroll
    for (int half = 0; half < 2; half++) {
        if (half) __syncthreads();          // pass-0 reads done before overwrite
#pragma unroll
        for (int ct = 0; ct < 4; ct++) {
            int c = half * 4 + ct;
            f32x4 bb4 = *(const f32x4*)(b2 + c * 16 + quad * 4);
            f32x4 mv;
#pragma unroll
            for (int g = 0; g < 4; g++)
                mv[g] = acc2[c][g] + bb4[g];
            *(f32x4*)(sMsg + (w * 16 + r) * MS3 + ct * 16 + quad * 4) = mv;
        }
        __syncthreads();

        // segmented reduction over dst-sorted rows; 8 strips x 16 edges,
        // one atomic per run per col
        int j = tid & 63, strip = tid >> 6;
        int e0 = strip * 16;
        float run = 0.f; int curd = -1;
        for (int q = 0; q < 16; q++) {
            int d = sDstV[e0 + q];
            float v = sMsg[(e0 + q) * MS3 + j];
            if (d != curd) {
                if (curd >= 0) atomicAdd(agg + (size_t)curd * H + half * 64 + j, run);
                run = 0.f; curd = d;
            }
            if (d >= 0) run += v;
        }
        if (curd >= 0) atomicAdd(agg + (size_t)curd * H + half * 64 + j, run);
    }
}

// ---------------- GRU cell: split-precision MFMA, mat-specialized waves ----
// last=1 (final layer): skip dead hb write and agg re-zero.
__global__ __launch_bounds__(1024, 4) void k_gru(
    float* __restrict__ h, __bf16* __restrict__ hb,
    float* __restrict__ agg,
    const __bf16* __restrict__ Wg,
    const float* __restrict__ bih, const float* __restrict__ bhh,
    int n_nodes, int last)
{
    const int nb = blockIdx.x * 32;
    const int tid = threadIdx.x;

    // phase 1: sIn[4][32][HS] bf16 (34816 B); phase 2: sEx[3][32][EXS] f32
    __shared__ char sRaw[3 * 32 * EXS * 4];          // 50688 B
    __bf16 (*sIn)[32][HS] = (__bf16(*)[32][HS])sRaw;
    float* sEx = (float*)sRaw;

    {   // stage + split inputs: one float4 of agg + h per thread
        int e = tid >> 5, c4 = (tid & 31) * 4;
        int n = nb + e;
        float4 av = {0.f, 0.f, 0.f, 0.f}, hv = {0.f, 0.f, 0.f, 0.f};
        if (n < n_nodes) {
            av = *(const float4*)(agg + (size_t)n * H + c4);
            hv = *(const float4*)(h + (size_t)n * H + c4);
            if (!last) {
                float4 z = {0.f, 0.f, 0.f, 0.f};
                *(float4*)(agg + (size_t)n * H + c4) = z;  // ready for next layer
            }
        }
        bf16x4 ahi, alo, hhi, hlo;
        float af[4] = {av.x, av.y, av.z, av.w};
        float hf[4] = {hv.x, hv.y, hv.z, hv.w};
#pragma unroll
        for (int c = 0; c < 4; c++) {
            __bf16 ah = (__bf16)af[c]; ahi[c] = ah; alo[c] = (__bf16)(af[c] - (float)ah);
            __bf16 hh = (__bf16)hf[c]; hhi[c] = hh; hlo[c] = (__bf16)(hf[c] - (float)hh);
        }
        *(bf16x4*)&sIn[0][e][c4] = ahi;
        *(bf16x4*)&sIn[1][e][c4] = alo;
        *(bf16x4*)&sIn[2][e][c4] = hhi;
        *(bf16x4*)&sIn[3][e][c4] = hlo;
    }
    __syncthreads();

    const int lane = tid & 63, w = tid >> 6;     // w: 0..15
    const int r = lane & 15, quad = lane >> 4;
    const int jt = w & 7;
    const int mat = w >> 3;

    f32x4 acc[2][3];                     // [m][gate]
#pragma unroll
    for (int m = 0; m < 2; m++)
#pragma unroll
        for (int g = 0; g < 3; g++)
            acc[m][g] = (f32x4){0.f, 0.f, 0.f, 0.f};

    bf16x8 B[2][6];                      // [buf][g*2+split]
#pragma unroll
    for (int g = 0; g < 3; g++)
#pragma unroll
    for (int sp = 0; sp < 2; sp++)
        B[0][g * 2 + sp] = *(const bf16x8*)(Wg +
            ((((size_t)(mat * 2 + sp) * 4 + 0) * 24 + (g * 8 + jt)) * 64 + lane) * 8);

#pragma unroll
    for (int kc = 0; kc < 4; kc++) {
        const int cur = kc & 1, nxt = cur ^ 1;
        if (kc < 3) {
#pragma unroll
            for (int g = 0; g < 3; g++)
#pragma unroll
            for (int sp = 0; sp < 2; sp++)
                B[nxt][g * 2 + sp] = *(const bf16x8*)(Wg +
                    ((((size_t)(mat * 2 + sp) * 4 + (kc + 1)) * 24 + (g * 8 + jt)) * 64 + lane) * 8);
        }
        bf16x8 A[2][2];
#pragma unroll
        for (int m = 0; m < 2; m++)
#pragma unroll
            for (int s = 0; s < 2; s++)
                A[m][s] = *(const bf16x8*)&sIn[mat * 2 + s][m * 16 + r][kc * 32 + quad * 8];
#pragma unroll
        for (int g = 0; g < 3; g++) {
            bf16x8 bhi = B[cur][g * 2 + 0];
            bf16x8 blo = B[cur][g * 2 + 1];
#pragma unroll
            for (int m = 0; m < 2; m++) {
                acc[m][g] = __builtin_amdgcn_mfma_f32_16x16x32_bf16(
                    A[m][0], bhi, acc[m][g], 0, 0, 0);
                acc[m][g] = __builtin_amdgcn_mfma_f32_16x16x32_bf16(
                    A[m][0], blo, acc[m][g], 0, 0, 0);
                acc[m][g] = __builtin_amdgcn_mfma_f32_16x16x32_bf16(
                    A[m][1], bhi, acc[m][g], 0, 0, 0);
            }
        }
    }

    __syncthreads();   // all sIn reads done before sEx overwrites

    const int jcol = jt * 16 + r;
    if (mat == 1) {    // publish recurrent-gate accs
#pragma unroll
        for (int m = 0; m < 2; m++)
#pragma unroll
        for (int g = 0; g < 3; g++)
#pragma unroll
        for (int g4 = 0; g4 < 4; g4++) {
            int e = m * 16 + quad * 4 + g4;
            sEx[(g * 32 + e) * EXS + jcol] = acc[m][g][g4];
        }
    }
    __syncthreads();

    if (mat == 0) {    // gate epilogue
        float br_ = bih[jcol], bz_ = bih[128 + jcol], bn_ = bih[256 + jcol];
        float cr = bhh[jcol], cz = bhh[128 + jcol], cn = bhh[256 + jcol];
#pragma unroll
        for (int m = 0; m < 2; m++)
#pragma unroll
        for (int g4 = 0; g4 < 4; g4++) {
            int e = m * 16 + quad * 4 + g4;
            int n = nb + e;
            if (n < n_nodes) {
                float ir = acc[m][0][g4], iz = acc[m][1][g4], in_ = acc[m][2][g4];
                float hr = sEx[(0 * 32 + e) * EXS + jcol];
                float hz = sEx[(1 * 32 + e) * EXS + jcol];
                float hn = sEx[(2 * 32 + e) * EXS + jcol];
                float hold = h[(size_t)n * H + jcol];
                float rr = 1.f / (1.f + expf(-(ir + br_ + hr + cr)));
                float zz = 1.f / (1.f + expf(-(iz + bz_ + hz + cz)));
                float nv = tanhf(in_ + bn_ + rr * (hn + cn));
                float out = (1.f - zz) * nv + zz * hold;
                h[(size_t)n * H + jcol] = out;
                if (!last) hb[(size_t)n * H + jcol] = (__bf16)out;
            }
        }
    }
}

// ---------------- readout: split-precision MFMA ----------------------------
__global__ __launch_bounds__(256, 4) void k_readout(
    const float* __restrict__ h, const __bf16* __restrict__ Wr1s,
    const float* __restrict__ br1, const float* __restrict__ Wr2,
    const float* __restrict__ br2, float* __restrict__ out, int n_out)
{
    const int nb = blockIdx.x * 32;
    const int tid = threadIdx.x;
    __shared__ __bf16 sIn[2][32][HS];   // h hi/lo (17.4 KB)
    __shared__ float sRed[4][32];

#pragma unroll
    for (int v = 0; v < 4; v++) {
        int idx = tid + 256 * v;            // float4 id, 1024 total
        int e = idx >> 5, c4 = (idx & 31) * 4;
        int n = nb + e;
        float4 hv = {0.f, 0.f, 0.f, 0.f};
        if (n < n_out)
            hv = *(const float4*)(h + (size_t)n * H + c4);
        float hf[4] = {hv.x, hv.y, hv.z, hv.w};
        bf16x4 hhi, hlo;
#pragma unroll
        for (int c = 0; c < 4; c++) {
            __bf16 hh = (__bf16)hf[c];
            hhi[c] = hh; hlo[c] = (__bf16)(hf[c] - (float)hh);
        }
        *(bf16x4*)&sIn[0][e][c4] = hhi;
        *(bf16x4*)&sIn[1][e][c4] = hlo;
    }
    __syncthreads();

    const int lane = tid & 63, w = tid >> 6;
    const int r = lane & 15, quad = lane >> 4;

    f32x4 acc[2][2];                 // [m][j]
#pragma unroll
    for (int m = 0; m < 2; m++)
#pragma unroll
        for (int j = 0; j < 2; j++)
            acc[m][j] = (f32x4){0.f, 0.f, 0.f, 0.f};

#pragma unroll
    for (int kc = 0; kc < 4; kc++) {
        bf16x8 A[2][2];
#pragma unroll
        for (int m = 0; m < 2; m++)
#pragma unroll
            for (int s = 0; s < 2; s++)
                A[m][s] = *(const bf16x8*)&sIn[s][m * 16 + r][kc * 32 + quad * 8];
#pragma unroll
        for (int j = 0; j < 2; j++) {
            int jtg = w * 2 + j;
            bf16x8 bhi = *(const bf16x8*)(Wr1s +
                ((size_t)(0 * 4 + kc) * 8 + jtg) * 512 + lane * 8);
            bf16x8 blo = *(const bf16x8*)(Wr1s +
                ((size_t)(1 * 4 + kc) * 8 + jtg) * 512 + lane * 8);
#pragma unroll
            for (int m = 0; m < 2; m++) {
                acc[m][j] = __builtin_amdgcn_mfma_f32_16x16x32_bf16(
                    A[m][0], bhi, acc[m][j], 0, 0, 0);
                acc[m][j] = __builtin_amdgcn_mfma_f32_16x16x32_bf16(
                    A[m][0], blo, acc[m][j], 0, 0, 0);
                acc[m][j] = __builtin_amdgcn_mfma_f32_16x16x32_bf16(
                    A[m][1], bhi, acc[m][j], 0, 0, 0);
            }
        }
    }

    float part[2][4];
#pragma unroll
    for (int m = 0; m < 2; m++)
#pragma unroll
        for (int g = 0; g < 4; g++) part[m][g] = 0.f;
#pragma unroll
    for (int j = 0; j < 2; j++) {
        int col = (w * 2 + j) * 16 + r;
        float b1v = br1[col], w2v = Wr2[col];
#pragma unroll
        for (int m = 0; m < 2; m++)
#pragma unroll
            for (int g = 0; g < 4; g++)
                part[m][g] += fmaxf(acc[m][j][g] + b1v, 0.f) * w2v;
    }
#pragma unroll
    for (int mask = 1; mask < 16; mask <<= 1)
#pragma unroll
        for (int m = 0; m < 2; m++)
#pragma unroll
            for (int g = 0; g < 4; g++)
                part[m][g] += __shfl_xor(part[m][g], mask, 16);
    if (r == 0) {
#pragma unroll
        for (int m = 0; m < 2; m++)
#pragma unroll
            for (int g = 0; g < 4; g++)
                sRed[w][m * 16 + quad * 4 + g] = part[m][g];
    }
    __syncthreads();
    if (tid < 32) {
        int n = nb + tid;
        if (n < n_out)
            out[n] = sRed[0][tid] + sRed[1][tid] + sRed[2][tid] + sRed[3][tid]
                     + br2[0];
    }
}

// ---------------------------------------------------------------------------
extern "C" void kernel_launch(void* const* d_in, const int* in_sizes, int n_in,
                              void* d_out, int out_size, void* d_ws, size_t ws_size,
                              hipStream_t stream)
{
    const float* x      = (const float*)d_in[0];
    const int*   eidx   = (const int*)d_in[1];
    const int*   etype  = (const int*)d_in[2];
    const float* Win    = (const float*)d_in[4];
    const float* bin    = (const float*)d_in[5];
    const float* W1     = (const float*)d_in[6];   // (3,2,256,128)
    const float* b1     = (const float*)d_in[7];   // (3,2,128)
    const float* W2     = (const float*)d_in[8];   // (3,2,128,128)
    const float* b2     = (const float*)d_in[9];   // (3,2,128)
    const float* Wih    = (const float*)d_in[10];  // (3,128,384)
    const float* bih    = (const float*)d_in[11];  // (3,384)
    const float* Whh    = (const float*)d_in[12];  // (3,128,384)
    const float* bhh    = (const float*)d_in[13];  // (3,384)
    const float* Wr1    = (const float*)d_in[14];
    const float* br1    = (const float*)d_in[15];
    const float* Wr2    = (const float*)d_in[16];
    const float* br2    = (const float*)d_in[17];

    const int n_nodes = in_sizes[0] / FEAT;
    const int n_edges = in_sizes[1] / 2;
    const int L = 3;
    const size_t nh = (size_t)n_nodes * H;

    const int* src = eidx;
    const int* dst = eidx + n_edges;

    // workspace carve-up
    float*  h    = (float*)d_ws;                    // 25.6 MB
    float*  agg  = h + nh;                          // 25.6 MB
    __bf16* hb   = (__bf16*)(agg + nh);             // 12.8 MB
    __bf16* Wsw  = hb + nh;                         // WC_TOTAL bf16
    __bf16* Wg   = Wsw + WC_TOTAL;                  // 3*WG_PER_LAYER bf16
    __bf16* Wr1s = Wg + 3 * WG_PER_LAYER;           // WR_TOTAL bf16
    int* bucket  = (int*)(Wr1s + WR_TOTAL);         // n_edges
    int* cnt     = bucket + n_edges;                // 2*nn (also k_place cursors)
    int* offs    = cnt + 2 * n_nodes;               // 2*nn + 1
    int* bsum    = offs + 2 * n_nodes + 1;          // scan block sums

    const int nscan = 2 * n_nodes;
    const int nb = (nscan + 1023) / 1024;

    // one mega-prep kernel: weight swizzles + cnt zero + input proj + agg 0
    const long long prep_total = (long long)WC_TOTAL + 3 * WG_PER_LAYER
                               + WR_TOTAL + nscan + (long long)nh;
    k_prep<<<(int)((prep_total + 255) / 256), 256, 0, stream>>>(
        W1, W2, Wih, Whh, Wr1, x, Win, bin,
        Wsw, Wg, Wr1s, cnt, h, hb, agg, n_nodes);

    const int eb = (n_edges + 255) / 256;
    k_hist <<<eb, 256, 0, stream>>>(etype, dst, cnt, n_edges, n_nodes);
    k_scan1<<<nb, 1024, 0, stream>>>(cnt, bsum, nscan);
    k_scan2<<<1, 128, 0, stream>>>(bsum, offs, nb, nscan);
    k_scan3<<<nb, 1024, 0, stream>>>(cnt, bsum, offs, nscan);
    k_place<<<eb, 256, 0, stream>>>(etype, dst, offs, cnt, bucket, n_edges, n_nodes);

    const dim3 mgrid((n_edges + TE2 - 1) / TE2, 2);
    for (int l = 0; l < L; l++) {
        k_msg<<<mgrid, 512, 0, stream>>>(
            hb, bucket, offs, src, dst,
            Wsw + (size_t)l * 2 * 12 * 4096,
            b1 + (size_t)l * 2 * H, b2 + (size_t)l * 2 * H,
            agg, n_edges, n_nodes);
        k_gru<<<(n_nodes + 31) / 32, 1024, 0, stream>>>(
            h, hb, agg,
            Wg + (size_t)l * WG_PER_LAYER,
            bih + (size_t)l * 384, bhh + (size_t)l * 384,
            n_nodes, (l == L - 1) ? 1 : 0);
    }

    k_readout<<<(out_size + 31) / 32, 256, 0, stream>>>(
        h, Wr1s, br1, Wr2, br2, (float*)d_out, out_size);
}